// Round 1
// 389.755 us; speedup vs baseline: 1.1126x; 1.1126x over previous
//
#include <hip/hip_runtime.h>

#define L_SZ 200
#define RB 8
#define HS_STRIDE 72   // bf16 elems per H row: 64 + 8 pad (144 B, 16B-aligned)

typedef __attribute__((ext_vector_type(8))) short short8;   // 8 bf16 = 4 VGPRs (MFMA A/B frag)
typedef __attribute__((ext_vector_type(4))) float floatx4;  // MFMA C/D frag

__device__ __forceinline__ unsigned short f2bf(float f) {
    unsigned int u = __float_as_uint(f);
    unsigned int r = (u + 0x7fffu + ((u >> 16) & 1u)) >> 16;
    return (unsigned short)r;
}
__device__ __forceinline__ float bf2f(unsigned short h) {
    return __uint_as_float(((unsigned int)h) << 16);
}
__device__ __forceinline__ float wave_sum64(float v) {
    #pragma unroll
    for (int m = 1; m <= 32; m <<= 1) v += __shfl_xor(v, m, 64);
    return v;
}
__device__ __forceinline__ float wave_max64(float v) {
    #pragma unroll
    for (int m = 1; m <= 32; m <<= 1) v = fmaxf(v, __shfl_xor(v, m, 64));
    return v;
}
__device__ __forceinline__ unsigned int pk2(float a, float b) {
    return ((unsigned int)f2bf(b) << 16) | (unsigned int)f2bf(a);
}

// ---------------------------------------------------------------------------
// prep_kernel: batch-invariant tables + per-b cb, computed ONCE.
//   block 0      : T1t[j][k] = aW0[k][j] + aW0[192+k][j]   (64x64 f32, transposed)
//                  T2t[j][k] = aW0[128+k][j]               (64x64 f32, transposed)
//                  PW1 frag-packed bf16 of aW1: [(nt*2+ks)*64+lane]*8+i
//   blocks 1..1024: cb_ws[b][j] = ab0[j] + sum_k iemb_b[k]*(aW0[64+k][j]-aW0[192+k][j])
// ---------------------------------------------------------------------------
__global__ __launch_bounds__(256) void prep_kernel(
    const int* __restrict__ item_id, const float* __restrict__ item_W,
    const float* __restrict__ aW0, const float* __restrict__ ab0,
    const float* __restrict__ aW1,
    float* __restrict__ T1t, float* __restrict__ T2t,
    unsigned short* __restrict__ PW1, float* __restrict__ cb_ws)
{
    const int tid = threadIdx.x;
    if (blockIdx.x == 0) {
        for (int u = tid; u < 4096; u += 256) {
            int j = u >> 6, k = u & 63;
            T1t[j * 64 + k] = aW0[k * 64 + j] + aW0[(192 + k) * 64 + j];
            T2t[j * 64 + k] = aW0[(128 + k) * 64 + j];
        }
        for (int u = tid; u < 2048; u += 256) {
            int i = u & 7, lane = (u >> 3) & 63, f = u >> 9;
            int nt = f >> 1, ks = f & 1;
            int k = ks * 32 + (lane >> 4) * 8 + i;
            int n = nt * 16 + (lane & 15);
            PW1[u] = f2bf(aW1[k * 32 + n]);
        }
    } else {
        __shared__ float T3[64][64];   // [k][j]
        for (int u = tid; u < 4096; u += 256) {
            int k = u >> 6, j = u & 63;
            T3[k][j] = aW0[(64 + k) * 64 + j] - aW0[(192 + k) * 64 + j];
        }
        __syncthreads();
        const int bl = tid >> 6, j = tid & 63;
        const int b = (blockIdx.x - 1) * 4 + bl;
        const float* ie = item_W + (size_t)item_id[b] * 64;
        float acc = ab0[j];
        #pragma unroll 8
        for (int k = 0; k < 64; ++k) acc = fmaf(ie[k], T3[k][j], acc);
        cb_ws[(size_t)b * 64 + j] = acc;
    }
}

// ---------------------------------------------------------------------------
// attn_kernel: one block per batch element. 256 thr = 4 waves.
// Deep-issued gather: each thread owns 6-7 fixed (row, col8) units, reads seq
// ids straight from global (no pre-gather barrier), issues all 14x16B loads
// before any packing -> ~14 loads in flight per thread during staging.
// WeT build from prepacked T1t/T2t (8 coalesced float4 loads), bW1 from PW1
// (4 b128 loads), cb from cb_ws. LDS 38,624 B -> 4 blocks/CU.
// ---------------------------------------------------------------------------
__global__ __launch_bounds__(256, 4) void attn_kernel(
    const int* __restrict__ item_id, const int* __restrict__ hist_seq,
    const float* __restrict__ item_W, const float* __restrict__ hist_W,
    const float* __restrict__ T1t, const float* __restrict__ T2t,
    const unsigned short* __restrict__ PW1, const float* __restrict__ cb_ws,
    const float* __restrict__ ab1, const float* __restrict__ aW2,
    const float* __restrict__ ab2, float* __restrict__ pooled_ws)
{
    __shared__ __align__(16) unsigned char smem[38624];
    unsigned short* Hs  = (unsigned short*)(smem);           // 200 x 72 bf16 = 28800 B
    unsigned short* BB  = (unsigned short*)(smem + 28800);   // 8192 B: WeT -> scr -> pools
    int*   seq_sh = (int*)(smem + 36992);                    // 200 i32
    float* scores = (float*)(smem + 37792);                  // 200 f32
    float* red    = (float*)(smem + 38592);                  // 8 f32

    const int tid  = threadIdx.x;
    const int w    = tid >> 6;
    const int lane = tid & 63;
    const int b    = blockIdx.x;
    const int* hseq = hist_seq + b * L_SZ;

    // stage seq for mask use later (independent of gather addressing below)
    if (tid < L_SZ) seq_sh[tid] = hseq[tid];

    // ---- deep gather: rows rbase+32t (t<6), plus rows 192..199 for tid<64 ----
    const int rbase = tid >> 3, c8 = tid & 7;
    const bool extra = tid < 64;
    const int r6 = extra ? 192 + rbase : 0;
    const float* sp[7];
    #pragma unroll
    for (int t = 0; t < 6; ++t)
        sp[t] = hist_W + (size_t)hseq[rbase + t * 32] * 64 + c8 * 8;
    sp[6] = hist_W + (size_t)hseq[r6] * 64 + c8 * 8;
    float4 f0[7], f1[7];
    #pragma unroll
    for (int t = 0; t < 7; ++t) {
        f0[t] = *(const float4*)sp[t];
        f1[t] = *(const float4*)(sp[t] + 4);
    }

    // ---- issue batch-invariant loads while the gather is in flight ----
    const int c = lane & 15, q = lane >> 4;
    short8 bW1[2][2];
    #pragma unroll
    for (int nt = 0; nt < 2; ++nt)
        #pragma unroll
        for (int ks = 0; ks < 2; ++ks)
            bW1[nt][ks] = *(const short8*)(PW1 + ((nt * 2 + ks) * 64 + lane) * 8);
    float cbr[4];
    #pragma unroll
    for (int nt = 0; nt < 4; ++nt) cbr[nt] = cb_ws[(size_t)b * 64 + nt * 16 + c];
    float ab1r[2], aw2r[2];
    #pragma unroll
    for (int nt = 0; nt < 2; ++nt) {
        ab1r[nt] = ab1[nt * 16 + c];
        aw2r[nt] = aW2[nt * 16 + c];
    }
    const float ab2s = ab2[0];

    // ---- pack gather -> Hs (per-use vmcnt keeps later loads outstanding) ----
    #pragma unroll
    for (int t = 0; t < 6; ++t) {
        uint4 pk;
        pk.x = pk2(f0[t].x, f0[t].y); pk.y = pk2(f0[t].z, f0[t].w);
        pk.z = pk2(f1[t].x, f1[t].y); pk.w = pk2(f1[t].z, f1[t].w);
        *(uint4*)(Hs + (rbase + t * 32) * HS_STRIDE + c8 * 8) = pk;
    }
    if (extra) {
        uint4 pk;
        pk.x = pk2(f0[6].x, f0[6].y); pk.y = pk2(f0[6].z, f0[6].w);
        pk.z = pk2(f1[6].x, f1[6].y); pk.w = pk2(f1[6].z, f1[6].w);
        *(uint4*)(Hs + r6 * HS_STRIDE + c8 * 8) = pk;
    }

    // ---- WeT build from prepacked tables: bf16(T1 + iemb*T2), swizzled ----
    {
        const float* irow = item_W + (size_t)item_id[b] * 64;
        const int j0 = tid >> 3;   // 0..31
        float4 em0 = *(const float4*)(irow + c8 * 8);
        float4 em1 = *(const float4*)(irow + c8 * 8 + 4);
        #pragma unroll
        for (int t = 0; t < 2; ++t) {
            int j = j0 + t * 32;
            const float* p1 = T1t + j * 64 + c8 * 8;
            const float* p2 = T2t + j * 64 + c8 * 8;
            float4 a0 = *(const float4*)p1, a1 = *(const float4*)(p1 + 4);
            float4 b0 = *(const float4*)p2, b1 = *(const float4*)(p2 + 4);
            float v[8];
            v[0] = a0.x + em0.x * b0.x; v[1] = a0.y + em0.y * b0.y;
            v[2] = a0.z + em0.z * b0.z; v[3] = a0.w + em0.w * b0.w;
            v[4] = a1.x + em1.x * b1.x; v[5] = a1.y + em1.y * b1.y;
            v[6] = a1.z + em1.z * b1.z; v[7] = a1.w + em1.w * b1.w;
            uint4 pk;
            pk.x = pk2(v[0], v[1]); pk.y = pk2(v[2], v[3]);
            pk.z = pk2(v[4], v[5]); pk.w = pk2(v[6], v[7]);
            *(uint4*)(BB + j * 64 + (c8 ^ (j & 7)) * 8) = pk;
        }
    }
    __syncthreads();

    // ---- hoist bW frags from swizzled WeT ----
    short8 bW[4][2];
    #pragma unroll
    for (int nt = 0; nt < 4; ++nt)
        #pragma unroll
        for (int ks = 0; ks < 2; ++ks)
            bW[nt][ks] = *(const short8*)(BB + (nt * 16 + c) * 64
                                             + ((4 * ks + q) ^ (c & 7)) * 8);
    __syncthreads();   // protects BB: WeT reads done before scr writes below

    unsigned short* scrw = BB + w * (16 * 64);
    const floatx4 zf = {0.f, 0.f, 0.f, 0.f};

    // ---- main: per M-tile  layer0 MFMA -> relu -> scr -> layer1 MFMA -> score ----
    // (tile 12 rows 200..207 read garbage beyond Hs -> rows are independent, masked)
    for (int mt = w; mt < 13; mt += 4) {
        const int rowbase = mt * 16;
        floatx4 acc0[4] = {zf, zf, zf, zf};
        #pragma unroll
        for (int ks = 0; ks < 2; ++ks) {
            short8 a = *(const short8*)(Hs + (rowbase + c) * HS_STRIDE + ks * 32 + q * 8);
            acc0[0] = __builtin_amdgcn_mfma_f32_16x16x32_bf16(a, bW[0][ks], acc0[0], 0, 0, 0);
            acc0[1] = __builtin_amdgcn_mfma_f32_16x16x32_bf16(a, bW[1][ks], acc0[1], 0, 0, 0);
            acc0[2] = __builtin_amdgcn_mfma_f32_16x16x32_bf16(a, bW[2][ks], acc0[2], 0, 0, 0);
            acc0[3] = __builtin_amdgcn_mfma_f32_16x16x32_bf16(a, bW[3][ks], acc0[3], 0, 0, 0);
        }
        // epilogue: +cb, relu, bf16; C-layout (col=c,row=q*4+r) -> swizzled scr
        #pragma unroll
        for (int nt = 0; nt < 4; ++nt)
            #pragma unroll
            for (int r = 0; r < 4; ++r) {
                float h = fmaxf(acc0[nt][r] + cbr[nt], 0.f);
                int row = q * 4 + r;
                int gp = (2 * nt + (c >> 3)) ^ (row & 7);
                scrw[row * 64 + gp * 8 + (c & 7)] = f2bf(h);
            }
        floatx4 acc1[2] = {zf, zf};
        #pragma unroll
        for (int ks = 0; ks < 2; ++ks) {
            short8 a1 = *(const short8*)(scrw + c * 64 + ((4 * ks + q) ^ (c & 7)) * 8);
            acc1[0] = __builtin_amdgcn_mfma_f32_16x16x32_bf16(a1, bW1[0][ks], acc1[0], 0, 0, 0);
            acc1[1] = __builtin_amdgcn_mfma_f32_16x16x32_bf16(a1, bW1[1][ks], acc1[1], 0, 0, 0);
        }
        // layer2: relu -> *aW2 -> reduce over the 16 col-lanes
        float s[4];
        #pragma unroll
        for (int r = 0; r < 4; ++r)
            s[r] = fmaxf(acc1[0][r] + ab1r[0], 0.f) * aw2r[0]
                 + fmaxf(acc1[1][r] + ab1r[1], 0.f) * aw2r[1];
        #pragma unroll
        for (int m = 1; m <= 8; m <<= 1)
            #pragma unroll
            for (int r = 0; r < 4; ++r) s[r] += __shfl_xor(s[r], m, 64);
        if (c == 0) {
            #pragma unroll
            for (int r = 0; r < 4; ++r) {
                int l = rowbase + q * 4 + r;
                if (l < L_SZ)
                    scores[l] = (seq_sh[l] == 0) ? -1.0e9f : (s[r] + ab2s);
            }
        }
    }
    __syncthreads();

    // ---- masked softmax over 200 scores ----
    float s0 = (tid < L_SZ) ? scores[tid] : -3.0e38f;
    float mx = wave_max64(s0);
    if (lane == 0) red[w] = mx;
    __syncthreads();
    mx = fmaxf(fmaxf(red[0], red[1]), fmaxf(red[2], red[3]));
    float e = (tid < L_SZ) ? __expf(s0 - mx) : 0.f;
    float sm = wave_sum64(e);
    if (lane == 0) red[4 + w] = sm;
    __syncthreads();
    const float winv = 1.f / ((red[4] + red[5]) + (red[6] + red[7]));
    if (tid < L_SZ) scores[tid] = e * winv;
    __syncthreads();

    // ---- pooled[j] = sum_l w_l * H[l][j]; 8 row-groups x (2 cols / lane) ----
    float* pools = (float*)BB;   // scr dead now
    {
        int g  = (w << 1) | (lane >> 5);
        int jj = lane & 31;
        int l0 = g * 26, l1 = (l0 + 26 < L_SZ) ? l0 + 26 : L_SZ;
        float p0 = 0.f, p1 = 0.f;
        for (int l = l0; l < l1; ++l) {
            float wt = scores[l];
            unsigned int pv = *(const unsigned int*)(Hs + l * HS_STRIDE + jj * 2);
            p0 = fmaf(wt, bf2f((unsigned short)(pv & 0xffffu)), p0);
            p1 = fmaf(wt, bf2f((unsigned short)(pv >> 16)), p1);
        }
        float2 pp = {p0, p1};
        *(float2*)&pools[g * 64 + jj * 2] = pp;
    }
    __syncthreads();
    if (tid < 64) {
        float sum = 0.f;
        #pragma unroll
        for (int g = 0; g < 8; ++g) sum += pools[g * 64 + tid];
        pooled_ws[(size_t)b * 64 + tid] = sum;
    }
}

// Main MLP: 244 -> 256 -> 128 -> 1 -> sigmoid. One block per RB=8 rows.
__global__ __launch_bounds__(256) void mlp_kernel(
    const int* __restrict__ user_id, const int* __restrict__ item_id,
    const int* __restrict__ item_cat, const int* __restrict__ item_dur,
    const float* __restrict__ user_dense, const float* __restrict__ item_dense,
    const float* __restrict__ user_W, const float* __restrict__ item_W,
    const float* __restrict__ cat_W, const float* __restrict__ dur_W,
    const float* __restrict__ mW0, const float* __restrict__ mb0,
    const float* __restrict__ mW1, const float* __restrict__ mb1,
    const float* __restrict__ mW2, const float* __restrict__ mb2,
    const float* __restrict__ pooled_ws, float* __restrict__ out)
{
    __shared__ __align__(16) float xT[244][RB];
    __shared__ __align__(16) float h0T[256][RB];
    __shared__ __align__(16) float h1T[128][RB];
    __shared__ __align__(16) float part[128][RB];

    const int tid = threadIdx.x;
    const int b0 = blockIdx.x * RB;

    for (int idx = tid; idx < 244 * RB; idx += 256) {
        int r = idx / 244;
        int c = idx - r * 244;
        int b = b0 + r;
        float v;
        if (c < 64)       v = user_W[(size_t)user_id[b] * 64 + c];
        else if (c < 128) v = item_W[(size_t)item_id[b] * 64 + (c - 64)];
        else if (c < 144) v = cat_W[item_cat[b] * 16 + (c - 128)];
        else if (c < 152) v = dur_W[item_dur[b] * 8 + (c - 144)];
        else if (c < 177) v = user_dense[b * 25 + (c - 152)];
        else if (c < 180) v = item_dense[b * 3 + (c - 177)];
        else              v = pooled_ws[(size_t)b * 64 + (c - 180)];
        xT[c][r] = v;
    }
    __syncthreads();

    {
        float acc[RB];
        const float bias = mb0[tid];
        #pragma unroll
        for (int r = 0; r < RB; ++r) acc[r] = bias;
        #pragma unroll 4
        for (int k = 0; k < 244; ++k) {
            float wk = mW0[k * 256 + tid];
            float4 xa = *(const float4*)&xT[k][0];
            float4 xb = *(const float4*)&xT[k][4];
            acc[0] = fmaf(wk, xa.x, acc[0]);
            acc[1] = fmaf(wk, xa.y, acc[1]);
            acc[2] = fmaf(wk, xa.z, acc[2]);
            acc[3] = fmaf(wk, xa.w, acc[3]);
            acc[4] = fmaf(wk, xb.x, acc[4]);
            acc[5] = fmaf(wk, xb.y, acc[5]);
            acc[6] = fmaf(wk, xb.z, acc[6]);
            acc[7] = fmaf(wk, xb.w, acc[7]);
        }
        #pragma unroll
        for (int r = 0; r < RB; ++r) h0T[tid][r] = fmaxf(acc[r], 0.f);
    }
    __syncthreads();

    const int jj = tid & 127;
    const int half = tid >> 7;
    {
        float acc[RB];
        #pragma unroll
        for (int r = 0; r < RB; ++r) acc[r] = 0.f;
        #pragma unroll 4
        for (int t = 0; t < 128; ++t) {
            int k = half * 128 + t;
            float wk = mW1[k * 128 + jj];
            float4 ha = *(const float4*)&h0T[k][0];
            float4 hb = *(const float4*)&h0T[k][4];
            acc[0] = fmaf(wk, ha.x, acc[0]);
            acc[1] = fmaf(wk, ha.y, acc[1]);
            acc[2] = fmaf(wk, ha.z, acc[2]);
            acc[3] = fmaf(wk, ha.w, acc[3]);
            acc[4] = fmaf(wk, hb.x, acc[4]);
            acc[5] = fmaf(wk, hb.y, acc[5]);
            acc[6] = fmaf(wk, hb.z, acc[6]);
            acc[7] = fmaf(wk, hb.w, acc[7]);
        }
        if (half == 1) {
            #pragma unroll
            for (int r = 0; r < RB; ++r) part[jj][r] = acc[r];
        }
        __syncthreads();
        if (half == 0) {
            const float bias = mb1[jj];
            #pragma unroll
            for (int r = 0; r < RB; ++r)
                h1T[jj][r] = fmaxf(acc[r] + part[jj][r] + bias, 0.f);
        }
    }
    __syncthreads();

    if (tid < RB) {
        const int r = tid;
        float a0 = mb2[0], a1 = 0.f;
        #pragma unroll 8
        for (int k = 0; k < 128; k += 2) {
            a0 = fmaf(h1T[k][r],     mW2[k],     a0);
            a1 = fmaf(h1T[k + 1][r], mW2[k + 1], a1);
        }
        float a = a0 + a1;
        out[b0 + r] = 1.f / (1.f + __expf(-a));
    }
}

extern "C" void kernel_launch(void* const* d_in, const int* in_sizes, int n_in,
                              void* d_out, int out_size, void* d_ws, size_t ws_size,
                              hipStream_t stream) {
    (void)in_sizes; (void)n_in; (void)out_size; (void)ws_size;
    const int*   user_id    = (const int*)d_in[0];
    const int*   item_id    = (const int*)d_in[1];
    const int*   item_cat   = (const int*)d_in[2];
    const int*   item_dur   = (const int*)d_in[3];
    const float* user_dense = (const float*)d_in[4];
    const float* item_dense = (const float*)d_in[5];
    const int*   hist_seq   = (const int*)d_in[6];
    const float* user_W     = (const float*)d_in[7];
    const float* item_W     = (const float*)d_in[8];
    const float* cat_W      = (const float*)d_in[9];
    const float* dur_W      = (const float*)d_in[10];
    const float* hist_W     = (const float*)d_in[11];
    const float* aW0 = (const float*)d_in[12];
    const float* ab0 = (const float*)d_in[13];
    const float* aW1 = (const float*)d_in[14];
    const float* ab1 = (const float*)d_in[15];
    const float* aW2 = (const float*)d_in[16];
    const float* ab2 = (const float*)d_in[17];
    const float* mW0 = (const float*)d_in[18];
    const float* mb0 = (const float*)d_in[19];
    const float* mW1 = (const float*)d_in[20];
    const float* mb1 = (const float*)d_in[21];
    const float* mW2 = (const float*)d_in[22];
    const float* mb2 = (const float*)d_in[23];
    float* out = (float*)d_out;

    // workspace layout: pooled 1MB | cb 1MB | T1t 16KB | T2t 16KB | PW1 4KB
    char* ws = (char*)d_ws;
    float* pooled_ws = (float*)ws;                               // 4096*64 f32
    float* cb_ws     = (float*)(ws + (1u << 20));                // 4096*64 f32
    float* T1t       = (float*)(ws + (2u << 20));                // 64*64 f32
    float* T2t       = (float*)(ws + (2u << 20) + 16384);        // 64*64 f32
    unsigned short* PW1 = (unsigned short*)(ws + (2u << 20) + 32768); // 2048 bf16

    prep_kernel<<<1025, 256, 0, stream>>>(item_id, item_W, aW0, ab0, aW1,
                                          T1t, T2t, PW1, cb_ws);
    attn_kernel<<<4096, 256, 0, stream>>>(item_id, hist_seq, item_W, hist_W,
                                          T1t, T2t, PW1, cb_ws,
                                          ab1, aW2, ab2, pooled_ws);
    mlp_kernel<<<4096 / RB, 256, 0, stream>>>(user_id, item_id, item_cat, item_dur,
                                              user_dense, item_dense,
                                              user_W, item_W, cat_W, dur_W,
                                              mW0, mb0, mW1, mb1, mW2, mb2,
                                              pooled_ws, out);
}

// Round 2
// 388.744 us; speedup vs baseline: 1.1155x; 1.0026x over previous
//
#include <hip/hip_runtime.h>

#define L_SZ 200
#define RB 8
#define HS_STRIDE 72   // bf16 elems per H row: 64 + 8 pad (144 B, 16B-aligned)

typedef __attribute__((ext_vector_type(8))) short short8;   // 8 bf16 = 4 VGPRs (MFMA A/B frag)
typedef __attribute__((ext_vector_type(4))) float floatx4;  // MFMA C/D frag

__device__ __forceinline__ unsigned short f2bf(float f) {
    unsigned int u = __float_as_uint(f);
    unsigned int r = (u + 0x7fffu + ((u >> 16) & 1u)) >> 16;
    return (unsigned short)r;
}
__device__ __forceinline__ float bf2f(unsigned short h) {
    return __uint_as_float(((unsigned int)h) << 16);
}
__device__ __forceinline__ float wave_sum64(float v) {
    #pragma unroll
    for (int m = 1; m <= 32; m <<= 1) v += __shfl_xor(v, m, 64);
    return v;
}
__device__ __forceinline__ float wave_max64(float v) {
    #pragma unroll
    for (int m = 1; m <= 32; m <<= 1) v = fmaxf(v, __shfl_xor(v, m, 64));
    return v;
}
__device__ __forceinline__ unsigned int pk2(float a, float b) {
    return ((unsigned int)f2bf(b) << 16) | (unsigned int)f2bf(a);
}

// ---------------------------------------------------------------------------
// prep_kernel: batch-invariant tables + per-b cb, computed ONCE.
//   block 0      : T1t[j][k] = aW0[k][j] + aW0[192+k][j]   (64x64 f32, transposed)
//                  T2t[j][k] = aW0[128+k][j]               (64x64 f32, transposed)
//                  PW1 frag-packed bf16 of aW1
//     -> transpose via padded LDS (stride 65): global reads AND writes both
//        coalesced. (Round-1 version did stride-256B gathers in a single
//        block: ~3K split transactions serialized on one CU = ~41 us.)
//   blocks 1..1024: cb_ws[b][j] = ab0[j] + sum_k iemb_b[k]*(aW0[64+k][j]-aW0[192+k][j])
//     T3 staged coalesced into the same (aliased) LDS buffer, stride 65.
// ---------------------------------------------------------------------------
__global__ __launch_bounds__(256) void prep_kernel(
    const int* __restrict__ item_id, const float* __restrict__ item_W,
    const float* __restrict__ aW0, const float* __restrict__ ab0,
    const float* __restrict__ aW1,
    float* __restrict__ T1t, float* __restrict__ T2t,
    unsigned short* __restrict__ PW1, float* __restrict__ cb_ws)
{
    __shared__ float shbuf[3 * 64 * 65];   // 49,920 B
    const int tid = threadIdx.x;
    if (blockIdx.x == 0) {
        // coalesced load of aW0 rows {0..63}, {128..191}, {192..255} into LDS
        #pragma unroll
        for (int t = 0; t < 3; ++t) {
            const int r0 = (t == 0) ? 0 : (t == 1) ? 128 : 192;
            for (int u = tid; u < 1024; u += 256) {          // 64 rows x 16 float4
                int k = u >> 4, c4 = u & 15;
                float4 v = *(const float4*)(aW0 + (r0 + k) * 64 + c4 * 4);
                float* dst = shbuf + t * 4160 + k * 65 + c4 * 4;
                dst[0] = v.x; dst[1] = v.y; dst[2] = v.z; dst[3] = v.w;
            }
        }
        __syncthreads();
        // transposed reads from LDS (pad 65 -> banks spread), coalesced writes
        for (int u = tid; u < 4096; u += 256) {
            int j = u >> 6, k = u & 63;
            T1t[u] = shbuf[k * 65 + j] + shbuf[2 * 4160 + k * 65 + j];
            T2t[u] = shbuf[4160 + k * 65 + j];
        }
        for (int u = tid; u < 2048; u += 256) {
            int i = u & 7, lane = (u >> 3) & 63, f = u >> 9;
            int nt = f >> 1, ks = f & 1;
            int k = ks * 32 + (lane >> 4) * 8 + i;
            int n = nt * 16 + (lane & 15);
            PW1[u] = f2bf(aW1[k * 32 + n]);
        }
    } else {
        // stage T3[k][j] (stride 65), reads coalesced (consecutive tid -> j)
        for (int u = tid; u < 4096; u += 256) {
            int k = u >> 6, j = u & 63;
            shbuf[k * 65 + j] = aW0[(64 + k) * 64 + j] - aW0[(192 + k) * 64 + j];
        }
        __syncthreads();
        const int bl = tid >> 6, j = tid & 63;
        const int b = (blockIdx.x - 1) * 4 + bl;
        const float* ie = item_W + (size_t)item_id[b] * 64;
        float acc = ab0[j];
        #pragma unroll 8
        for (int k = 0; k < 64; ++k) acc = fmaf(ie[k], shbuf[k * 65 + j], acc);
        cb_ws[(size_t)b * 64 + j] = acc;
    }
}

// ---------------------------------------------------------------------------
// attn_kernel: one block per batch element. 256 thr = 4 waves.
// Deep-issued gather: each thread owns 6-7 fixed (row, col8) units, reads seq
// ids straight from global (no pre-gather barrier), issues all 14x16B loads
// before any packing -> ~14 loads in flight per thread during staging.
// WeT build from prepacked T1t/T2t (8 coalesced float4 loads), bW1 from PW1
// (4 b128 loads), cb from cb_ws. LDS 38,624 B -> 4 blocks/CU.
// ---------------------------------------------------------------------------
__global__ __launch_bounds__(256, 4) void attn_kernel(
    const int* __restrict__ item_id, const int* __restrict__ hist_seq,
    const float* __restrict__ item_W, const float* __restrict__ hist_W,
    const float* __restrict__ T1t, const float* __restrict__ T2t,
    const unsigned short* __restrict__ PW1, const float* __restrict__ cb_ws,
    const float* __restrict__ ab1, const float* __restrict__ aW2,
    const float* __restrict__ ab2, float* __restrict__ pooled_ws)
{
    __shared__ __align__(16) unsigned char smem[38624];
    unsigned short* Hs  = (unsigned short*)(smem);           // 200 x 72 bf16 = 28800 B
    unsigned short* BB  = (unsigned short*)(smem + 28800);   // 8192 B: WeT -> scr -> pools
    int*   seq_sh = (int*)(smem + 36992);                    // 200 i32
    float* scores = (float*)(smem + 37792);                  // 200 f32
    float* red    = (float*)(smem + 38592);                  // 8 f32

    const int tid  = threadIdx.x;
    const int w    = tid >> 6;
    const int lane = tid & 63;
    const int b    = blockIdx.x;
    const int* hseq = hist_seq + b * L_SZ;

    // stage seq for mask use later (independent of gather addressing below)
    if (tid < L_SZ) seq_sh[tid] = hseq[tid];

    // ---- deep gather: rows rbase+32t (t<6), plus rows 192..199 for tid<64 ----
    const int rbase = tid >> 3, c8 = tid & 7;
    const bool extra = tid < 64;
    const int r6 = extra ? 192 + rbase : 0;
    const float* sp[7];
    #pragma unroll
    for (int t = 0; t < 6; ++t)
        sp[t] = hist_W + (size_t)hseq[rbase + t * 32] * 64 + c8 * 8;
    sp[6] = hist_W + (size_t)hseq[r6] * 64 + c8 * 8;
    float4 f0[7], f1[7];
    #pragma unroll
    for (int t = 0; t < 7; ++t) {
        f0[t] = *(const float4*)sp[t];
        f1[t] = *(const float4*)(sp[t] + 4);
    }

    // ---- issue batch-invariant loads while the gather is in flight ----
    const int c = lane & 15, q = lane >> 4;
    short8 bW1[2][2];
    #pragma unroll
    for (int nt = 0; nt < 2; ++nt)
        #pragma unroll
        for (int ks = 0; ks < 2; ++ks)
            bW1[nt][ks] = *(const short8*)(PW1 + ((nt * 2 + ks) * 64 + lane) * 8);
    float cbr[4];
    #pragma unroll
    for (int nt = 0; nt < 4; ++nt) cbr[nt] = cb_ws[(size_t)b * 64 + nt * 16 + c];
    float ab1r[2], aw2r[2];
    #pragma unroll
    for (int nt = 0; nt < 2; ++nt) {
        ab1r[nt] = ab1[nt * 16 + c];
        aw2r[nt] = aW2[nt * 16 + c];
    }
    const float ab2s = ab2[0];

    // ---- pack gather -> Hs (per-use vmcnt keeps later loads outstanding) ----
    #pragma unroll
    for (int t = 0; t < 6; ++t) {
        uint4 pk;
        pk.x = pk2(f0[t].x, f0[t].y); pk.y = pk2(f0[t].z, f0[t].w);
        pk.z = pk2(f1[t].x, f1[t].y); pk.w = pk2(f1[t].z, f1[t].w);
        *(uint4*)(Hs + (rbase + t * 32) * HS_STRIDE + c8 * 8) = pk;
    }
    if (extra) {
        uint4 pk;
        pk.x = pk2(f0[6].x, f0[6].y); pk.y = pk2(f0[6].z, f0[6].w);
        pk.z = pk2(f1[6].x, f1[6].y); pk.w = pk2(f1[6].z, f1[6].w);
        *(uint4*)(Hs + r6 * HS_STRIDE + c8 * 8) = pk;
    }

    // ---- WeT build from prepacked tables: bf16(T1 + iemb*T2), swizzled ----
    {
        const float* irow = item_W + (size_t)item_id[b] * 64;
        const int j0 = tid >> 3;   // 0..31
        float4 em0 = *(const float4*)(irow + c8 * 8);
        float4 em1 = *(const float4*)(irow + c8 * 8 + 4);
        #pragma unroll
        for (int t = 0; t < 2; ++t) {
            int j = j0 + t * 32;
            const float* p1 = T1t + j * 64 + c8 * 8;
            const float* p2 = T2t + j * 64 + c8 * 8;
            float4 a0 = *(const float4*)p1, a1 = *(const float4*)(p1 + 4);
            float4 b0 = *(const float4*)p2, b1 = *(const float4*)(p2 + 4);
            float v[8];
            v[0] = a0.x + em0.x * b0.x; v[1] = a0.y + em0.y * b0.y;
            v[2] = a0.z + em0.z * b0.z; v[3] = a0.w + em0.w * b0.w;
            v[4] = a1.x + em1.x * b1.x; v[5] = a1.y + em1.y * b1.y;
            v[6] = a1.z + em1.z * b1.z; v[7] = a1.w + em1.w * b1.w;
            uint4 pk;
            pk.x = pk2(v[0], v[1]); pk.y = pk2(v[2], v[3]);
            pk.z = pk2(v[4], v[5]); pk.w = pk2(v[6], v[7]);
            *(uint4*)(BB + j * 64 + (c8 ^ (j & 7)) * 8) = pk;
        }
    }
    __syncthreads();

    // ---- hoist bW frags from swizzled WeT ----
    short8 bW[4][2];
    #pragma unroll
    for (int nt = 0; nt < 4; ++nt)
        #pragma unroll
        for (int ks = 0; ks < 2; ++ks)
            bW[nt][ks] = *(const short8*)(BB + (nt * 16 + c) * 64
                                             + ((4 * ks + q) ^ (c & 7)) * 8);
    __syncthreads();   // protects BB: WeT reads done before scr writes below

    unsigned short* scrw = BB + w * (16 * 64);
    const floatx4 zf = {0.f, 0.f, 0.f, 0.f};

    // ---- main: per M-tile  layer0 MFMA -> relu -> scr -> layer1 MFMA -> score ----
    // (tile 12 rows 200..207 read garbage beyond Hs -> rows are independent, masked)
    for (int mt = w; mt < 13; mt += 4) {
        const int rowbase = mt * 16;
        floatx4 acc0[4] = {zf, zf, zf, zf};
        #pragma unroll
        for (int ks = 0; ks < 2; ++ks) {
            short8 a = *(const short8*)(Hs + (rowbase + c) * HS_STRIDE + ks * 32 + q * 8);
            acc0[0] = __builtin_amdgcn_mfma_f32_16x16x32_bf16(a, bW[0][ks], acc0[0], 0, 0, 0);
            acc0[1] = __builtin_amdgcn_mfma_f32_16x16x32_bf16(a, bW[1][ks], acc0[1], 0, 0, 0);
            acc0[2] = __builtin_amdgcn_mfma_f32_16x16x32_bf16(a, bW[2][ks], acc0[2], 0, 0, 0);
            acc0[3] = __builtin_amdgcn_mfma_f32_16x16x32_bf16(a, bW[3][ks], acc0[3], 0, 0, 0);
        }
        // epilogue: +cb, relu, bf16; C-layout (col=c,row=q*4+r) -> swizzled scr
        #pragma unroll
        for (int nt = 0; nt < 4; ++nt)
            #pragma unroll
            for (int r = 0; r < 4; ++r) {
                float h = fmaxf(acc0[nt][r] + cbr[nt], 0.f);
                int row = q * 4 + r;
                int gp = (2 * nt + (c >> 3)) ^ (row & 7);
                scrw[row * 64 + gp * 8 + (c & 7)] = f2bf(h);
            }
        floatx4 acc1[2] = {zf, zf};
        #pragma unroll
        for (int ks = 0; ks < 2; ++ks) {
            short8 a1 = *(const short8*)(scrw + c * 64 + ((4 * ks + q) ^ (c & 7)) * 8);
            acc1[0] = __builtin_amdgcn_mfma_f32_16x16x32_bf16(a1, bW1[0][ks], acc1[0], 0, 0, 0);
            acc1[1] = __builtin_amdgcn_mfma_f32_16x16x32_bf16(a1, bW1[1][ks], acc1[1], 0, 0, 0);
        }
        // layer2: relu -> *aW2 -> reduce over the 16 col-lanes
        float s[4];
        #pragma unroll
        for (int r = 0; r < 4; ++r)
            s[r] = fmaxf(acc1[0][r] + ab1r[0], 0.f) * aw2r[0]
                 + fmaxf(acc1[1][r] + ab1r[1], 0.f) * aw2r[1];
        #pragma unroll
        for (int m = 1; m <= 8; m <<= 1)
            #pragma unroll
            for (int r = 0; r < 4; ++r) s[r] += __shfl_xor(s[r], m, 64);
        if (c == 0) {
            #pragma unroll
            for (int r = 0; r < 4; ++r) {
                int l = rowbase + q * 4 + r;
                if (l < L_SZ)
                    scores[l] = (seq_sh[l] == 0) ? -1.0e9f : (s[r] + ab2s);
            }
        }
    }
    __syncthreads();

    // ---- masked softmax over 200 scores ----
    float s0 = (tid < L_SZ) ? scores[tid] : -3.0e38f;
    float mx = wave_max64(s0);
    if (lane == 0) red[w] = mx;
    __syncthreads();
    mx = fmaxf(fmaxf(red[0], red[1]), fmaxf(red[2], red[3]));
    float e = (tid < L_SZ) ? __expf(s0 - mx) : 0.f;
    float sm = wave_sum64(e);
    if (lane == 0) red[4 + w] = sm;
    __syncthreads();
    const float winv = 1.f / ((red[4] + red[5]) + (red[6] + red[7]));
    if (tid < L_SZ) scores[tid] = e * winv;
    __syncthreads();

    // ---- pooled[j] = sum_l w_l * H[l][j]; 8 row-groups x (2 cols / lane) ----
    float* pools = (float*)BB;   // scr dead now
    {
        int g  = (w << 1) | (lane >> 5);
        int jj = lane & 31;
        int l0 = g * 26, l1 = (l0 + 26 < L_SZ) ? l0 + 26 : L_SZ;
        float p0 = 0.f, p1 = 0.f;
        for (int l = l0; l < l1; ++l) {
            float wt = scores[l];
            unsigned int pv = *(const unsigned int*)(Hs + l * HS_STRIDE + jj * 2);
            p0 = fmaf(wt, bf2f((unsigned short)(pv & 0xffffu)), p0);
            p1 = fmaf(wt, bf2f((unsigned short)(pv >> 16)), p1);
        }
        float2 pp = {p0, p1};
        *(float2*)&pools[g * 64 + jj * 2] = pp;
    }
    __syncthreads();
    if (tid < 64) {
        float sum = 0.f;
        #pragma unroll
        for (int g = 0; g < 8; ++g) sum += pools[g * 64 + tid];
        pooled_ws[(size_t)b * 64 + tid] = sum;
    }
}

// Main MLP: 244 -> 256 -> 128 -> 1 -> sigmoid. One block per RB=8 rows.
__global__ __launch_bounds__(256) void mlp_kernel(
    const int* __restrict__ user_id, const int* __restrict__ item_id,
    const int* __restrict__ item_cat, const int* __restrict__ item_dur,
    const float* __restrict__ user_dense, const float* __restrict__ item_dense,
    const float* __restrict__ user_W, const float* __restrict__ item_W,
    const float* __restrict__ cat_W, const float* __restrict__ dur_W,
    const float* __restrict__ mW0, const float* __restrict__ mb0,
    const float* __restrict__ mW1, const float* __restrict__ mb1,
    const float* __restrict__ mW2, const float* __restrict__ mb2,
    const float* __restrict__ pooled_ws, float* __restrict__ out)
{
    __shared__ __align__(16) float xT[244][RB];
    __shared__ __align__(16) float h0T[256][RB];
    __shared__ __align__(16) float h1T[128][RB];
    __shared__ __align__(16) float part[128][RB];

    const int tid = threadIdx.x;
    const int b0 = blockIdx.x * RB;

    for (int idx = tid; idx < 244 * RB; idx += 256) {
        int r = idx / 244;
        int c = idx - r * 244;
        int b = b0 + r;
        float v;
        if (c < 64)       v = user_W[(size_t)user_id[b] * 64 + c];
        else if (c < 128) v = item_W[(size_t)item_id[b] * 64 + (c - 64)];
        else if (c < 144) v = cat_W[item_cat[b] * 16 + (c - 128)];
        else if (c < 152) v = dur_W[item_dur[b] * 8 + (c - 144)];
        else if (c < 177) v = user_dense[b * 25 + (c - 152)];
        else if (c < 180) v = item_dense[b * 3 + (c - 177)];
        else              v = pooled_ws[(size_t)b * 64 + (c - 180)];
        xT[c][r] = v;
    }
    __syncthreads();

    {
        float acc[RB];
        const float bias = mb0[tid];
        #pragma unroll
        for (int r = 0; r < RB; ++r) acc[r] = bias;
        #pragma unroll 4
        for (int k = 0; k < 244; ++k) {
            float wk = mW0[k * 256 + tid];
            float4 xa = *(const float4*)&xT[k][0];
            float4 xb = *(const float4*)&xT[k][4];
            acc[0] = fmaf(wk, xa.x, acc[0]);
            acc[1] = fmaf(wk, xa.y, acc[1]);
            acc[2] = fmaf(wk, xa.z, acc[2]);
            acc[3] = fmaf(wk, xa.w, acc[3]);
            acc[4] = fmaf(wk, xb.x, acc[4]);
            acc[5] = fmaf(wk, xb.y, acc[5]);
            acc[6] = fmaf(wk, xb.z, acc[6]);
            acc[7] = fmaf(wk, xb.w, acc[7]);
        }
        #pragma unroll
        for (int r = 0; r < RB; ++r) h0T[tid][r] = fmaxf(acc[r], 0.f);
    }
    __syncthreads();

    const int jj = tid & 127;
    const int half = tid >> 7;
    {
        float acc[RB];
        #pragma unroll
        for (int r = 0; r < RB; ++r) acc[r] = 0.f;
        #pragma unroll 4
        for (int t = 0; t < 128; ++t) {
            int k = half * 128 + t;
            float wk = mW1[k * 128 + jj];
            float4 ha = *(const float4*)&h0T[k][0];
            float4 hb = *(const float4*)&h0T[k][4];
            acc[0] = fmaf(wk, ha.x, acc[0]);
            acc[1] = fmaf(wk, ha.y, acc[1]);
            acc[2] = fmaf(wk, ha.z, acc[2]);
            acc[3] = fmaf(wk, ha.w, acc[3]);
            acc[4] = fmaf(wk, hb.x, acc[4]);
            acc[5] = fmaf(wk, hb.y, acc[5]);
            acc[6] = fmaf(wk, hb.z, acc[6]);
            acc[7] = fmaf(wk, hb.w, acc[7]);
        }
        if (half == 1) {
            #pragma unroll
            for (int r = 0; r < RB; ++r) part[jj][r] = acc[r];
        }
        __syncthreads();
        if (half == 0) {
            const float bias = mb1[jj];
            #pragma unroll
            for (int r = 0; r < RB; ++r)
                h1T[jj][r] = fmaxf(acc[r] + part[jj][r] + bias, 0.f);
        }
    }
    __syncthreads();

    if (tid < RB) {
        const int r = tid;
        float a0 = mb2[0], a1 = 0.f;
        #pragma unroll 8
        for (int k = 0; k < 128; k += 2) {
            a0 = fmaf(h1T[k][r],     mW2[k],     a0);
            a1 = fmaf(h1T[k + 1][r], mW2[k + 1], a1);
        }
        float a = a0 + a1;
        out[b0 + r] = 1.f / (1.f + __expf(-a));
    }
}

extern "C" void kernel_launch(void* const* d_in, const int* in_sizes, int n_in,
                              void* d_out, int out_size, void* d_ws, size_t ws_size,
                              hipStream_t stream) {
    (void)in_sizes; (void)n_in; (void)out_size; (void)ws_size;
    const int*   user_id    = (const int*)d_in[0];
    const int*   item_id    = (const int*)d_in[1];
    const int*   item_cat   = (const int*)d_in[2];
    const int*   item_dur   = (const int*)d_in[3];
    const float* user_dense = (const float*)d_in[4];
    const float* item_dense = (const float*)d_in[5];
    const int*   hist_seq   = (const int*)d_in[6];
    const float* user_W     = (const float*)d_in[7];
    const float* item_W     = (const float*)d_in[8];
    const float* cat_W      = (const float*)d_in[9];
    const float* dur_W      = (const float*)d_in[10];
    const float* hist_W     = (const float*)d_in[11];
    const float* aW0 = (const float*)d_in[12];
    const float* ab0 = (const float*)d_in[13];
    const float* aW1 = (const float*)d_in[14];
    const float* ab1 = (const float*)d_in[15];
    const float* aW2 = (const float*)d_in[16];
    const float* ab2 = (const float*)d_in[17];
    const float* mW0 = (const float*)d_in[18];
    const float* mb0 = (const float*)d_in[19];
    const float* mW1 = (const float*)d_in[20];
    const float* mb1 = (const float*)d_in[21];
    const float* mW2 = (const float*)d_in[22];
    const float* mb2 = (const float*)d_in[23];
    float* out = (float*)d_out;

    // workspace layout: pooled 1MB | cb 1MB | T1t 16KB | T2t 16KB | PW1 4KB
    char* ws = (char*)d_ws;
    float* pooled_ws = (float*)ws;                               // 4096*64 f32
    float* cb_ws     = (float*)(ws + (1u << 20));                // 4096*64 f32
    float* T1t       = (float*)(ws + (2u << 20));                // 64*64 f32
    float* T2t       = (float*)(ws + (2u << 20) + 16384);        // 64*64 f32
    unsigned short* PW1 = (unsigned short*)(ws + (2u << 20) + 32768); // 2048 bf16

    prep_kernel<<<1025, 256, 0, stream>>>(item_id, item_W, aW0, ab0, aW1,
                                          T1t, T2t, PW1, cb_ws);
    attn_kernel<<<4096, 256, 0, stream>>>(item_id, hist_seq, item_W, hist_W,
                                          T1t, T2t, PW1, cb_ws,
                                          ab1, aW2, ab2, pooled_ws);
    mlp_kernel<<<4096 / RB, 256, 0, stream>>>(user_id, item_id, item_cat, item_dur,
                                              user_dense, item_dense,
                                              user_W, item_W, cat_W, dur_W,
                                              mW0, mb0, mW1, mb1, mW2, mb2,
                                              pooled_ws, out);
}